// Round 9
// baseline (1568.243 us; speedup 1.0000x reference)
//
#include <hip/hip_runtime.h>
#include <stdint.h>

#define N_NODES 100000
#define F 128
#define E_EDGES 1600000
#define KARY 8
#define NPERMS 4
#define NOUT 64

typedef __attribute__((ext_vector_type(8))) short bf16x8;
typedef __attribute__((ext_vector_type(4))) float f32x4;

// LDS-only barrier: waits lgkmcnt(0) (hs ordering) but does NOT drain vmcnt —
// __syncthreads would force vmcnt(0) and stall on unrelated global traffic.
#define BAR_LDS() asm volatile("s_waitcnt lgkmcnt(0)\n\ts_barrier" ::: "memory")

// ---------------- threefry2x32 (JAX-exact, 20 rounds) ----------------
__device__ __forceinline__ uint32_t rotl32(uint32_t v, int r) {
  return (v << r) | (v >> (32 - r));
}
__device__ __forceinline__ void tf2x32(uint32_t k0, uint32_t k1, uint32_t& x0, uint32_t& x1) {
  uint32_t ks2 = k0 ^ k1 ^ 0x1BD11BDAu;
  x0 += k0; x1 += k1;
  x0 += x1; x1 = rotl32(x1,13); x1 ^= x0;
  x0 += x1; x1 = rotl32(x1,15); x1 ^= x0;
  x0 += x1; x1 = rotl32(x1,26); x1 ^= x0;
  x0 += x1; x1 = rotl32(x1, 6); x1 ^= x0;
  x0 += k1; x1 += ks2 + 1u;
  x0 += x1; x1 = rotl32(x1,17); x1 ^= x0;
  x0 += x1; x1 = rotl32(x1,29); x1 ^= x0;
  x0 += x1; x1 = rotl32(x1,16); x1 ^= x0;
  x0 += x1; x1 = rotl32(x1,24); x1 ^= x0;
  x0 += ks2; x1 += k0 + 2u;
  x0 += x1; x1 = rotl32(x1,13); x1 ^= x0;
  x0 += x1; x1 = rotl32(x1,15); x1 ^= x0;
  x0 += x1; x1 = rotl32(x1,26); x1 ^= x0;
  x0 += x1; x1 = rotl32(x1, 6); x1 ^= x0;
  x0 += k0; x1 += k1 + 3u;
  x0 += x1; x1 = rotl32(x1,17); x1 ^= x0;
  x0 += x1; x1 = rotl32(x1,29); x1 ^= x0;
  x0 += x1; x1 = rotl32(x1,16); x1 ^= x0;
  x0 += x1; x1 = rotl32(x1,24); x1 ^= x0;
  x0 += k1; x1 += ks2 + 4u;
  x0 += x1; x1 = rotl32(x1,13); x1 ^= x0;
  x0 += x1; x1 = rotl32(x1,15); x1 ^= x0;
  x0 += x1; x1 = rotl32(x1,26); x1 ^= x0;
  x0 += x1; x1 = rotl32(x1, 6); x1 ^= x0;
  x0 += ks2; x1 += k0 + 5u;
}

// bf16 helpers
__device__ __forceinline__ unsigned short f2bf(float f) {  // RNE
  uint32_t u = __float_as_uint(f);
  uint32_t r = (u + 0x7FFFu + ((u >> 16) & 1u)) >> 16;
  return (unsigned short)r;
}
__device__ __forceinline__ float ubf(uint32_t u) { return __uint_as_float(u); }

// native transcendentals: single v_exp_f32 / v_rcp_f32.
__device__ __forceinline__ f32x4 exp2v(f32x4 x) {
  f32x4 r;
  r.x = __builtin_amdgcn_exp2f(x.x);
  r.y = __builtin_amdgcn_exp2f(x.y);
  r.z = __builtin_amdgcn_exp2f(x.z);
  r.w = __builtin_amdgcn_exp2f(x.w);
  return r;
}
__device__ __forceinline__ f32x4 rcpv(f32x4 x) {
  f32x4 r;
  r.x = __builtin_amdgcn_rcpf(x.x);
  r.y = __builtin_amdgcn_rcpf(x.y);
  r.z = __builtin_amdgcn_rcpf(x.z);
  r.w = __builtin_amdgcn_rcpf(x.w);
  return r;
}
__device__ __forceinline__ f32x4 sig4(f32x4 x) {
  return rcpv(1.0f + exp2v(x * -1.44269504f));
}
__device__ __forceinline__ f32x4 tanh4(f32x4 x) {
  return 1.0f - 2.0f * rcpv(exp2v(x * 2.88539008f) + 1.0f);
}
__device__ __forceinline__ float sigf(float x) {
  return __builtin_amdgcn_rcpf(1.0f + __builtin_amdgcn_exp2f(x * -1.44269504f));
}

// ---------------- CSR build ----------------
#define HIST_BLK (E_EDGES / 256)  // 6250

// fat kernel: histogram (blocks 0..6249) + weight prep (next 256 blocks)
__global__ __launch_bounds__(256) void k_hist_prepw(
    const int2* __restrict__ adj, int* __restrict__ deg,
    const float* __restrict__ w_ih, const float* __restrict__ w_hh,
    const float* __restrict__ b_ih, const float* __restrict__ b_hh,
    const float* __restrict__ weight,
    short* __restrict__ wihb, short* __restrict__ whb,
    short* __restrict__ wobT, float4* __restrict__ bq) {
  int b = blockIdx.x;
  if (b < HIST_BLK) {
    int e = b * 256 + threadIdx.x;
    atomicAdd(&deg[adj[e].x], 1);
  } else {
    int t = (b - HIST_BLK) * 256 + threadIdx.x;  // 0 .. 65535
    wihb[t] = (short)f2bf(w_ih[t]);
    whb[t] = (short)f2bf(w_hh[t]);
    if (t < 2 * F * NOUT) {
      int n = t & 63, k = t >> 6;
      wobT[n * 256 + k] = (short)f2bf(weight[k * NOUT + n]);
    }
    if (t < F)
      bq[t] = make_float4(b_ih[t] + b_hh[t], b_ih[F + t] + b_hh[F + t],
                          b_ih[2 * F + t] + b_hh[2 * F + t], b_ih[3 * F + t] + b_hh[3 * F + t]);
  }
}

__global__ void k_scan(const int* __restrict__ deg, int* __restrict__ roff) {
  __shared__ int sums[1024];
  const int tid = threadIdx.x;
  const int CH = (N_NODES + 1023) / 1024;  // 98
  int base = tid * CH;
  int s = 0;
  for (int i = 0; i < CH; ++i) {
    int idx = base + i;
    if (idx < N_NODES) s += deg[idx];
  }
  sums[tid] = s;
  __syncthreads();
  for (int off = 1; off < 1024; off <<= 1) {
    int v = (tid >= off) ? sums[tid - off] : 0;
    __syncthreads();
    sums[tid] += v;
    __syncthreads();
  }
  int run = sums[tid] - s;
  for (int i = 0; i < CH; ++i) {
    int idx = base + i;
    if (idx < N_NODES) { roff[idx] = run; run += deg[idx]; }
  }
}

__global__ void k_scatter(const int2* __restrict__ adj, const int* __restrict__ roff,
                          int* __restrict__ cursor, int2* __restrict__ csr) {
  int e = blockIdx.x * blockDim.x + threadIdx.x;
  if (e < E_EDGES) {
    int2 a = adj[e];
    int pos = roff[a.x] + atomicAdd(&cursor[a.x], 1);
    csr[pos] = make_int2(a.y, e);  // (dst, edge_id)
  }
}

#define HS_LD 136  // 128 + 8 pad shorts
#define SEL_BLK ((N_NODES + 255) / 256)  // 391

// fat kernel: top-8 selection (blocks 0..390, latency/VALU-bound) overlapped
// with x-side-gates MFMA GEMM (remaining 3125 blocks, memory/MFMA-bound).
__global__ __launch_bounds__(256) void k_sel_xg(
    const int2* __restrict__ csr, const int* __restrict__ roff,
    const int* __restrict__ deg, int* __restrict__ sel, int* __restrict__ lens,
    const float* __restrict__ feat, const short* __restrict__ wihb,
    const float4* __restrict__ bq, ushort4* __restrict__ xgq) {
  __shared__ short as_[32 * HS_LD];
  if (blockIdx.x < SEL_BLK) {
    // ---------------- selection (4 perms fused, JAX lexsort-exact) ----------
    int n = blockIdx.x * 256 + threadIdx.x;
    if (n >= N_NODES) return;
    uint32_t pk0[NPERMS], pk1[NPERMS];
#pragma unroll
    for (int p = 0; p < NPERMS; ++p) {
      uint32_t a = 0u, b = (uint32_t)p;
      tf2x32(0u, 42u, a, b);
      pk0[p] = a; pk1[p] = b;
    }
    int off = roff[n], d = deg[n];
    unsigned long long key[NPERMS][KARY];
    int nbr[NPERMS][KARY];
#pragma unroll
    for (int p = 0; p < NPERMS; ++p)
#pragma unroll
      for (int i = 0; i < KARY; ++i) { key[p][i] = ~0ULL; nbr[p][i] = -1; }
    for (int e = 0; e < d; ++e) {
      int2 ent = csr[off + e];
#pragma unroll
      for (int p = 0; p < NPERMS; ++p) {
        uint32_t x0 = 0u, x1 = (uint32_t)ent.y;
        tf2x32(pk0[p], pk1[p], x0, x1);
        uint32_t bits = x0 ^ x1;
        unsigned long long k = ((unsigned long long)(bits >> 9) << 21) | (unsigned)ent.y;
        if (k < key[p][KARY - 1]) {
          key[p][KARY - 1] = k; nbr[p][KARY - 1] = ent.x;
#pragma unroll
          for (int s = KARY - 1; s >= 1; --s) {
            if (key[p][s] < key[p][s - 1]) {
              unsigned long long tk = key[p][s]; key[p][s] = key[p][s - 1]; key[p][s - 1] = tk;
              int tn = nbr[p][s]; nbr[p][s] = nbr[p][s - 1]; nbr[p][s - 1] = tn;
            }
          }
        }
      }
    }
    int L = d < KARY ? d : KARY;
    lens[n] = L;
#pragma unroll
    for (int p = 0; p < NPERMS; ++p)
#pragma unroll
      for (int t = 0; t < KARY; ++t)
        sel[((size_t)p * N_NODES + n) * KARY + t] = (t < L) ? nbr[p][t] : -1;
  } else {
    // ---------------- x-side gates via MFMA: 32 nodes/block ----------------
    const int tid = threadIdx.x;
    const int w = tid >> 6, l = tid & 63;
    const int l15 = l & 15, q = l >> 4;
    const int nb = (blockIdx.x - SEL_BLK) * 32;
#pragma unroll
    for (int i = 0; i < 4; ++i) {
      int idx = tid + i * 256;  // 1024 float4 = 32 rows x 128 cols
      int row = idx >> 5, c4 = (idx & 31) * 4;
      float4 v = *(const float4*)&feat[(size_t)(nb + row) * F + c4];
      ushort4 s;
      s.x = f2bf(v.x); s.y = f2bf(v.y); s.z = f2bf(v.z); s.w = f2bf(v.w);
      *(ushort4*)&as_[row * HS_LD + c4] = s;
    }
    __syncthreads();

    f32x4 acc[2][2][4];
#pragma unroll
    for (int mt = 0; mt < 2; ++mt)
#pragma unroll
      for (int ft = 0; ft < 2; ++ft)
#pragma unroll
        for (int g4 = 0; g4 < 4; ++g4) acc[mt][ft][g4] = (f32x4){0.f, 0.f, 0.f, 0.f};

    const short* ab = as_ + l15 * HS_LD + q * 8;
#pragma unroll
    for (int kt = 0; kt < 4; ++kt) {
      bf16x8 a0 = *(const bf16x8*)(ab + kt * 32);
      bf16x8 a1 = *(const bf16x8*)(ab + 16 * HS_LD + kt * 32);
#pragma unroll
      for (int g4 = 0; g4 < 4; ++g4)
#pragma unroll
        for (int ft = 0; ft < 2; ++ft) {
          bf16x8 b = *(const bf16x8*)(wihb + (size_t)(g4 * 128 + 16 * ft + 32 * w + l15) * F + q * 8 + kt * 32);
          acc[0][ft][g4] = __builtin_amdgcn_mfma_f32_16x16x32_bf16(a0, b, acc[0][ft][g4], 0, 0, 0);
          acc[1][ft][g4] = __builtin_amdgcn_mfma_f32_16x16x32_bf16(a1, b, acc[1][ft][g4], 0, 0, 0);
        }
    }
#pragma unroll
    for (int mt = 0; mt < 2; ++mt)
#pragma unroll
      for (int ft = 0; ft < 2; ++ft) {
        int fi = 32 * w + 16 * ft + l15;
        float4 bb = bq[fi];
#pragma unroll
        for (int r = 0; r < 4; ++r) {
          int node = nb + mt * 16 + q * 4 + r;
          ushort4 o;
          o.x = f2bf(acc[mt][ft][0][r] + bb.x);
          o.y = f2bf(acc[mt][ft][1][r] + bb.y);
          o.z = f2bf(acc[mt][ft][2][r] + bb.z);
          o.w = f2bf(acc[mt][ft][3][r] + bb.w);
          xgq[(size_t)node * F + fi] = o;
        }
      }
  }
}

// ---------------- fused LSTM via MFMA, B register-persistent ----------------
// M=32 seqs (8 nodes x 4 perms), N=512 gates, K=128. Wave w owns fi slice
// [32w,32w+32). R5-proven loop body (unconditional MFMA, runtime t-loop,
// gathers at step top consumed same step). NEW: hs is DOUBLE-BUFFERED in LDS
// -> the mid-step barrier (epilogue-write vs MFMA-read hazard) is gone;
// ONE lgkm-only barrier per step. Frozen sequences copy h forward into the
// write buffer (rare: ~1.3% of nodes have deg<8).
// R6/R7/R8 lesson: NO cross-step register state, NO branches in the t-loop —
// both spill to scratch at this register pressure.
#define LB 8
__global__ __launch_bounds__(256, 2) void k_lstm(const short* __restrict__ whb,
                                                 const ushort4* __restrict__ xgq,
                                                 const int* __restrict__ sel,
                                                 const int* __restrict__ lens,
                                                 float* __restrict__ hneigh) {
  __shared__ short hs[2][32 * HS_LD];  // 17408 B double buffer
  __shared__ int sel_l[32][9];
  const int tid = threadIdx.x;
  const int w = tid >> 6;
  const int l = tid & 63;
  const int l15 = l & 15, q = l >> 4;
  const int nb = blockIdx.x * LB;
  const char* xgb = (const char*)xgq;
  const int fi8 = (32 * w + l15) * 8;  // byte offset of this lane's ft=0 quad

  {
    int m = tid >> 3, t = tid & 7;
    int node = nb + (m >> 2), p = m & 3;
    sel_l[m][t] = sel[((size_t)p * N_NODES + node) * KARY + t];
  }
  {  // zero-init buffer 0 (read at t=0)
    int* h32 = (int*)hs[0];
    for (int i = tid; i < 32 * HS_LD / 2; i += 256) h32[i] = 0;
  }
  uint32_t lp = 0;
#pragma unroll
  for (int i = 0; i < 8; ++i) lp |= (uint32_t)lens[nb + i] << (4 * i);

  // persistent B: breg[kt][g4][ft]  (128 VGPRs)
  bf16x8 breg[4][4][2];
#pragma unroll
  for (int kt = 0; kt < 4; ++kt)
#pragma unroll
    for (int g4 = 0; g4 < 4; ++g4)
#pragma unroll
      for (int ft = 0; ft < 2; ++ft)
        breg[kt][g4][ft] = *(const bf16x8*)(whb + (size_t)(g4 * 128 + 16 * ft + 32 * w + l15) * F + q * 8 + kt * 32);

  f32x4 cst[2][2];
#pragma unroll
  for (int mt = 0; mt < 2; ++mt)
#pragma unroll
    for (int ft = 0; ft < 2; ++ft) cst[mt][ft] = (f32x4){0.f, 0.f, 0.f, 0.f};

  __syncthreads();  // sel_l + hs[0] visible

  for (int t = 0; t < KARY; ++t) {
    // ---- prefetch this step's xg quads; latency hides under the MFMA phase
    uint2 xr[2][4][2];  // [mt][r][ft]: (i|f<<16, g|o<<16)
#pragma unroll
    for (int mt = 0; mt < 2; ++mt)
#pragma unroll
      for (int r = 0; r < 4; ++r) {
        int seq = mt * 16 + q * 4 + r;
        int v = sel_l[seq][t];
        v = v < 0 ? 0 : v;
        int off = (v << 10) + fi8;
        xr[mt][r][0] = *(const uint2*)(xgb + off);
        xr[mt][r][1] = *(const uint2*)(xgb + off + 128);
      }

    const short* abase = hs[t & 1] + l15 * HS_LD + q * 8;   // MFMA read buffer
    const short* rb = hs[t & 1];                            // epilogue copy-fwd src
    short* wb = hs[(t & 1) ^ 1];                            // epilogue write buffer

    // ---- MFMA phase (reads hs[t&1]; step t-1's barrier made it visible)
    f32x4 acc[2][2][4];
#pragma unroll
    for (int mt = 0; mt < 2; ++mt)
#pragma unroll
      for (int ft = 0; ft < 2; ++ft)
#pragma unroll
        for (int g4 = 0; g4 < 4; ++g4) acc[mt][ft][g4] = (f32x4){0.f, 0.f, 0.f, 0.f};

#pragma unroll
    for (int kt = 0; kt < 4; ++kt) {
      bf16x8 a0 = *(const bf16x8*)(abase + 0 * 16 * HS_LD + kt * 32);
      bf16x8 a1 = *(const bf16x8*)(abase + 1 * 16 * HS_LD + kt * 32);
#pragma unroll
      for (int g4 = 0; g4 < 4; ++g4)
#pragma unroll
        for (int ft = 0; ft < 2; ++ft) {
          acc[0][ft][g4] = __builtin_amdgcn_mfma_f32_16x16x32_bf16(a0, breg[kt][g4][ft], acc[0][ft][g4], 0, 0, 0);
          acc[1][ft][g4] = __builtin_amdgcn_mfma_f32_16x16x32_bf16(a1, breg[kt][g4][ft], acc[1][ft][g4], 0, 0, 0);
        }
    }
    // NO barrier here: epilogue writes go to the other buffer.

    // ---- epilogue, vectorized over r (4 perms of one node; `live` uniform)
#pragma unroll
    for (int mt = 0; mt < 2; ++mt) {
      int len = (lp >> (4 * (mt * 4 + q))) & 15;
      bool live = t < len;
#pragma unroll
      for (int ft = 0; ft < 2; ++ft) {
        f32x4 xi, xf, xg_, xo;
#pragma unroll
        for (int r = 0; r < 4; ++r) {
          uint2 x = xr[mt][r][ft];
          xi[r] = ubf(x.x << 16);
          xf[r] = ubf(x.x & 0xffff0000u);
          xg_[r] = ubf(x.y << 16);
          xo[r] = ubf(x.y & 0xffff0000u);
        }
        f32x4 ii = sig4(acc[mt][ft][0] + xi);
        f32x4 ff = sig4(acc[mt][ft][1] + xf);
        f32x4 gg = tanh4(acc[mt][ft][2] + xg_);
        f32x4 oo = sig4(acc[mt][ft][3] + xo);
        f32x4 cn = ff * cst[mt][ft] + ii * gg;
        int base = (mt * 16 + q * 4) * HS_LD + 32 * w + 16 * ft + l15;
        if (live) {
          cst[mt][ft] = cn;
          f32x4 hh = oo * tanh4(cn);
#pragma unroll
          for (int r = 0; r < 4; ++r)
            wb[base + r * HS_LD] = (short)(__float_as_uint(hh[r]) >> 16);  // trunc bf16
        } else {
          // frozen state: carry h forward into the write buffer
#pragma unroll
          for (int r = 0; r < 4; ++r)
            wb[base + r * HS_LD] = rb[base + r * HS_LD];
        }
      }
    }
    BAR_LDS();  // write buffer committed; gathers (vmcnt) unaffected
  }

#pragma unroll
  for (int mt = 0; mt < 2; ++mt) {
    int node = nb + mt * 4 + q;
#pragma unroll
    for (int ft = 0; ft < 2; ++ft) {
      int fi = 32 * w + 16 * ft + l15;
      f32x4 cc = cst[mt][ft];
      hneigh[(size_t)node * F + fi] = (cc.x + cc.y + cc.z + cc.w) * 0.25f;
    }
  }
}

// ---------------- head via MFMA: 64 nodes/block, N=64, K=256 ----------------
#define OS_LD 264  // 256 + 8 pad shorts
__global__ __launch_bounds__(256) void k_out(const float* __restrict__ feat,
                                             const float* __restrict__ hn,
                                             const short* __restrict__ wobT,
                                             const float* __restrict__ bias,
                                             float* __restrict__ out) {
  __shared__ short as_[64 * OS_LD];  // 33792 B
  const int tid = threadIdx.x;
  const int w = tid >> 6, l = tid & 63;
  const int l15 = l & 15, q = l >> 4;
  const int nb = blockIdx.x * 64;
#pragma unroll
  for (int i = 0; i < 16; ++i) {
    int idx = tid + i * 256;  // 4096 float4 = 64 rows x 256 cols
    int row = idx >> 6, c4 = (idx & 63) * 4;
    int node = nb + row;
    if (node > N_NODES - 1) node = N_NODES - 1;
    float4 v = (c4 < 128) ? *(const float4*)&feat[(size_t)node * F + c4]
                          : *(const float4*)&hn[(size_t)node * F + (c4 - 128)];
    ushort4 s;
    s.x = f2bf(v.x); s.y = f2bf(v.y); s.z = f2bf(v.z); s.w = f2bf(v.w);
    *(ushort4*)&as_[row * OS_LD + c4] = s;
  }
  __syncthreads();

  f32x4 acc[4];
#pragma unroll
  for (int nt = 0; nt < 4; ++nt) acc[nt] = (f32x4){0.f, 0.f, 0.f, 0.f};

  const short* ab = as_ + (w * 16 + l15) * OS_LD + q * 8;
#pragma unroll
  for (int kt = 0; kt < 8; ++kt) {
    bf16x8 a = *(const bf16x8*)(ab + kt * 32);
#pragma unroll
    for (int nt = 0; nt < 4; ++nt) {
      bf16x8 b = *(const bf16x8*)(wobT + (size_t)(nt * 16 + l15) * 256 + q * 8 + kt * 32);
      acc[nt] = __builtin_amdgcn_mfma_f32_16x16x32_bf16(a, b, acc[nt], 0, 0, 0);
    }
  }
#pragma unroll
  for (int nt = 0; nt < 4; ++nt) {
    int col = nt * 16 + l15;
    float bb = bias[col];
#pragma unroll
    for (int r = 0; r < 4; ++r) {
      int node = nb + w * 16 + q * 4 + r;
      if (node < N_NODES)
        out[(size_t)node * NOUT + col] = sigf(acc[nt][r] + bb);
    }
  }
}

extern "C" void kernel_launch(void* const* d_in, const int* in_sizes, int n_in,
                              void* d_out, int out_size, void* d_ws, size_t ws_size,
                              hipStream_t stream) {
  const float* feat = (const float*)d_in[0];
  const int2* adj = (const int2*)d_in[1];
  const float* w_ih = (const float*)d_in[2];
  const float* w_hh = (const float*)d_in[3];
  const float* b_ih = (const float*)d_in[4];
  const float* b_hh = (const float*)d_in[5];
  const float* weight = (const float*)d_in[6];
  const float* bias = (const float*)d_in[7];
  float* out = (float*)d_out;

  size_t off = 0;
  auto take = [&](size_t bytes) -> void* {
    void* p = (char*)d_ws + off;
    off += (bytes + 255) & ~(size_t)255;
    return p;
  };
  int* deg = (int*)take((size_t)N_NODES * 4);
  int* roff = (int*)take((size_t)N_NODES * 4);
  int* cursor = (int*)take((size_t)N_NODES * 4);
  int2* csr = (int2*)take((size_t)E_EDGES * 8);
  int* sel = (int*)take((size_t)NPERMS * N_NODES * KARY * 4);
  int* lens = (int*)take((size_t)N_NODES * 4);
  short* wihb = (short*)take((size_t)4 * F * F * 2);
  short* whb = (short*)take((size_t)4 * F * F * 2);
  short* wobT = (short*)take((size_t)NOUT * 2 * F * 2);
  float4* bq = (float4*)take((size_t)F * 16);
  ushort4* xgq = (ushort4*)take((size_t)N_NODES * F * 8);
  float* hn = (float*)take((size_t)N_NODES * F * 4);
  (void)ws_size; (void)in_sizes; (void)n_in; (void)out_size;

  hipMemsetAsync(deg, 0, (size_t)N_NODES * 4, stream);
  hipMemsetAsync(cursor, 0, (size_t)N_NODES * 4, stream);

  k_hist_prepw<<<HIST_BLK + 256, 256, 0, stream>>>(adj, deg, w_ih, w_hh, b_ih, b_hh,
                                                   weight, wihb, whb, wobT, bq);
  k_scan<<<1, 1024, 0, stream>>>(deg, roff);
  k_scatter<<<(E_EDGES + 255) / 256, 256, 0, stream>>>(adj, roff, cursor, csr);
  k_sel_xg<<<SEL_BLK + N_NODES / 32, 256, 0, stream>>>(csr, roff, deg, sel, lens,
                                                       feat, wihb, bq, xgq);
  k_lstm<<<N_NODES / LB, 256, 0, stream>>>(whb, xgq, sel, lens, hn);
  k_out<<<(N_NODES + 63) / 64, 256, 0, stream>>>(feat, hn, wobT, bias, out);
}

// Round 10
// 1446.762 us; speedup vs baseline: 1.0840x; 1.0840x over previous
//
#include <hip/hip_runtime.h>
#include <stdint.h>

#define N_NODES 100000
#define F 128
#define E_EDGES 1600000
#define KARY 8
#define NPERMS 4
#define NOUT 64

typedef __attribute__((ext_vector_type(8))) short bf16x8;
typedef __attribute__((ext_vector_type(4))) float f32x4;

// ---------------- threefry2x32 (JAX-exact, 20 rounds) ----------------
__device__ __forceinline__ uint32_t rotl32(uint32_t v, int r) {
  return (v << r) | (v >> (32 - r));
}
__device__ __forceinline__ void tf2x32(uint32_t k0, uint32_t k1, uint32_t& x0, uint32_t& x1) {
  uint32_t ks2 = k0 ^ k1 ^ 0x1BD11BDAu;
  x0 += k0; x1 += k1;
  x0 += x1; x1 = rotl32(x1,13); x1 ^= x0;
  x0 += x1; x1 = rotl32(x1,15); x1 ^= x0;
  x0 += x1; x1 = rotl32(x1,26); x1 ^= x0;
  x0 += x1; x1 = rotl32(x1, 6); x1 ^= x0;
  x0 += k1; x1 += ks2 + 1u;
  x0 += x1; x1 = rotl32(x1,17); x1 ^= x0;
  x0 += x1; x1 = rotl32(x1,29); x1 ^= x0;
  x0 += x1; x1 = rotl32(x1,16); x1 ^= x0;
  x0 += x1; x1 = rotl32(x1,24); x1 ^= x0;
  x0 += ks2; x1 += k0 + 2u;
  x0 += x1; x1 = rotl32(x1,13); x1 ^= x0;
  x0 += x1; x1 = rotl32(x1,15); x1 ^= x0;
  x0 += x1; x1 = rotl32(x1,26); x1 ^= x0;
  x0 += x1; x1 = rotl32(x1, 6); x1 ^= x0;
  x0 += k0; x1 += k1 + 3u;
  x0 += x1; x1 = rotl32(x1,17); x1 ^= x0;
  x0 += x1; x1 = rotl32(x1,29); x1 ^= x0;
  x0 += x1; x1 = rotl32(x1,16); x1 ^= x0;
  x0 += x1; x1 = rotl32(x1,24); x1 ^= x0;
  x0 += k1; x1 += ks2 + 4u;
  x0 += x1; x1 = rotl32(x1,13); x1 ^= x0;
  x0 += x1; x1 = rotl32(x1,15); x1 ^= x0;
  x0 += x1; x1 = rotl32(x1,26); x1 ^= x0;
  x0 += x1; x1 = rotl32(x1, 6); x1 ^= x0;
  x0 += ks2; x1 += k0 + 5u;
}

// bf16 helpers
__device__ __forceinline__ unsigned short f2bf(float f) {  // RNE
  uint32_t u = __float_as_uint(f);
  uint32_t r = (u + 0x7FFFu + ((u >> 16) & 1u)) >> 16;
  return (unsigned short)r;
}
__device__ __forceinline__ float ubf(uint32_t u) { return __uint_as_float(u); }

// native transcendentals: single v_exp_f32 / v_rcp_f32.
__device__ __forceinline__ f32x4 exp2v(f32x4 x) {
  f32x4 r;
  r.x = __builtin_amdgcn_exp2f(x.x);
  r.y = __builtin_amdgcn_exp2f(x.y);
  r.z = __builtin_amdgcn_exp2f(x.z);
  r.w = __builtin_amdgcn_exp2f(x.w);
  return r;
}
__device__ __forceinline__ f32x4 rcpv(f32x4 x) {
  f32x4 r;
  r.x = __builtin_amdgcn_rcpf(x.x);
  r.y = __builtin_amdgcn_rcpf(x.y);
  r.z = __builtin_amdgcn_rcpf(x.z);
  r.w = __builtin_amdgcn_rcpf(x.w);
  return r;
}
__device__ __forceinline__ f32x4 sig4(f32x4 x) {
  return rcpv(1.0f + exp2v(x * -1.44269504f));
}
__device__ __forceinline__ f32x4 tanh4(f32x4 x) {
  return 1.0f - 2.0f * rcpv(exp2v(x * 2.88539008f) + 1.0f);
}
__device__ __forceinline__ float sigf(float x) {
  return __builtin_amdgcn_rcpf(1.0f + __builtin_amdgcn_exp2f(x * -1.44269504f));
}

// ---------------- CSR build ----------------
#define HIST_BLK (E_EDGES / 256)  // 6250

// fat kernel: histogram (blocks 0..6249) + weight prep (next 256 blocks)
__global__ __launch_bounds__(256) void k_hist_prepw(
    const int2* __restrict__ adj, int* __restrict__ deg,
    const float* __restrict__ w_ih, const float* __restrict__ w_hh,
    const float* __restrict__ b_ih, const float* __restrict__ b_hh,
    const float* __restrict__ weight,
    short* __restrict__ wihb, short* __restrict__ whb,
    short* __restrict__ wobT, float4* __restrict__ bq) {
  int b = blockIdx.x;
  if (b < HIST_BLK) {
    int e = b * 256 + threadIdx.x;
    atomicAdd(&deg[adj[e].x], 1);
  } else {
    int t = (b - HIST_BLK) * 256 + threadIdx.x;  // 0 .. 65535
    wihb[t] = (short)f2bf(w_ih[t]);
    whb[t] = (short)f2bf(w_hh[t]);
    if (t < 2 * F * NOUT) {
      int n = t & 63, k = t >> 6;
      wobT[n * 256 + k] = (short)f2bf(weight[k * NOUT + n]);
    }
    if (t < F)
      bq[t] = make_float4(b_ih[t] + b_hh[t], b_ih[F + t] + b_hh[F + t],
                          b_ih[2 * F + t] + b_hh[2 * F + t], b_ih[3 * F + t] + b_hh[3 * F + t]);
  }
}

__global__ void k_scan(const int* __restrict__ deg, int* __restrict__ roff) {
  __shared__ int sums[1024];
  const int tid = threadIdx.x;
  const int CH = (N_NODES + 1023) / 1024;  // 98
  int base = tid * CH;
  int s = 0;
  for (int i = 0; i < CH; ++i) {
    int idx = base + i;
    if (idx < N_NODES) s += deg[idx];
  }
  sums[tid] = s;
  __syncthreads();
  for (int off = 1; off < 1024; off <<= 1) {
    int v = (tid >= off) ? sums[tid - off] : 0;
    __syncthreads();
    sums[tid] += v;
    __syncthreads();
  }
  int run = sums[tid] - s;
  for (int i = 0; i < CH; ++i) {
    int idx = base + i;
    if (idx < N_NODES) { roff[idx] = run; run += deg[idx]; }
  }
}

__global__ void k_scatter(const int2* __restrict__ adj, const int* __restrict__ roff,
                          int* __restrict__ cursor, int2* __restrict__ csr) {
  int e = blockIdx.x * blockDim.x + threadIdx.x;
  if (e < E_EDGES) {
    int2 a = adj[e];
    int pos = roff[a.x] + atomicAdd(&cursor[a.x], 1);
    csr[pos] = make_int2(a.y, e);  // (dst, edge_id)
  }
}

#define HS_LD 136  // 128 + 8 pad shorts
#define SEL_BLK ((N_NODES + 255) / 256)  // 391

// fat kernel: top-8 selection (blocks 0..390, latency/VALU-bound) overlapped
// with x-side-gates MFMA GEMM (remaining 3125 blocks, memory/MFMA-bound).
__global__ __launch_bounds__(256) void k_sel_xg(
    const int2* __restrict__ csr, const int* __restrict__ roff,
    const int* __restrict__ deg, int* __restrict__ sel, int* __restrict__ lens,
    const float* __restrict__ feat, const short* __restrict__ wihb,
    const float4* __restrict__ bq, ushort4* __restrict__ xgq) {
  __shared__ short as_[32 * HS_LD];
  if (blockIdx.x < SEL_BLK) {
    // ---------------- selection (4 perms fused, JAX lexsort-exact) ----------
    int n = blockIdx.x * 256 + threadIdx.x;
    if (n >= N_NODES) return;
    uint32_t pk0[NPERMS], pk1[NPERMS];
#pragma unroll
    for (int p = 0; p < NPERMS; ++p) {
      uint32_t a = 0u, b = (uint32_t)p;
      tf2x32(0u, 42u, a, b);
      pk0[p] = a; pk1[p] = b;
    }
    int off = roff[n], d = deg[n];
    unsigned long long key[NPERMS][KARY];
    int nbr[NPERMS][KARY];
#pragma unroll
    for (int p = 0; p < NPERMS; ++p)
#pragma unroll
      for (int i = 0; i < KARY; ++i) { key[p][i] = ~0ULL; nbr[p][i] = -1; }
    for (int e = 0; e < d; ++e) {
      int2 ent = csr[off + e];
#pragma unroll
      for (int p = 0; p < NPERMS; ++p) {
        uint32_t x0 = 0u, x1 = (uint32_t)ent.y;
        tf2x32(pk0[p], pk1[p], x0, x1);
        uint32_t bits = x0 ^ x1;
        unsigned long long k = ((unsigned long long)(bits >> 9) << 21) | (unsigned)ent.y;
        if (k < key[p][KARY - 1]) {
          key[p][KARY - 1] = k; nbr[p][KARY - 1] = ent.x;
#pragma unroll
          for (int s = KARY - 1; s >= 1; --s) {
            if (key[p][s] < key[p][s - 1]) {
              unsigned long long tk = key[p][s]; key[p][s] = key[p][s - 1]; key[p][s - 1] = tk;
              int tn = nbr[p][s]; nbr[p][s] = nbr[p][s - 1]; nbr[p][s - 1] = tn;
            }
          }
        }
      }
    }
    int L = d < KARY ? d : KARY;
    lens[n] = L;
#pragma unroll
    for (int p = 0; p < NPERMS; ++p)
#pragma unroll
      for (int t = 0; t < KARY; ++t)
        sel[((size_t)p * N_NODES + n) * KARY + t] = (t < L) ? nbr[p][t] : -1;
  } else {
    // ---------------- x-side gates via MFMA: 32 nodes/block ----------------
    const int tid = threadIdx.x;
    const int w = tid >> 6, l = tid & 63;
    const int l15 = l & 15, q = l >> 4;
    const int nb = (blockIdx.x - SEL_BLK) * 32;
#pragma unroll
    for (int i = 0; i < 4; ++i) {
      int idx = tid + i * 256;  // 1024 float4 = 32 rows x 128 cols
      int row = idx >> 5, c4 = (idx & 31) * 4;
      float4 v = *(const float4*)&feat[(size_t)(nb + row) * F + c4];
      ushort4 s;
      s.x = f2bf(v.x); s.y = f2bf(v.y); s.z = f2bf(v.z); s.w = f2bf(v.w);
      *(ushort4*)&as_[row * HS_LD + c4] = s;
    }
    __syncthreads();

    f32x4 acc[2][2][4];
#pragma unroll
    for (int mt = 0; mt < 2; ++mt)
#pragma unroll
      for (int ft = 0; ft < 2; ++ft)
#pragma unroll
        for (int g4 = 0; g4 < 4; ++g4) acc[mt][ft][g4] = (f32x4){0.f, 0.f, 0.f, 0.f};

    const short* ab = as_ + l15 * HS_LD + q * 8;
#pragma unroll
    for (int kt = 0; kt < 4; ++kt) {
      bf16x8 a0 = *(const bf16x8*)(ab + kt * 32);
      bf16x8 a1 = *(const bf16x8*)(ab + 16 * HS_LD + kt * 32);
#pragma unroll
      for (int g4 = 0; g4 < 4; ++g4)
#pragma unroll
        for (int ft = 0; ft < 2; ++ft) {
          bf16x8 b = *(const bf16x8*)(wihb + (size_t)(g4 * 128 + 16 * ft + 32 * w + l15) * F + q * 8 + kt * 32);
          acc[0][ft][g4] = __builtin_amdgcn_mfma_f32_16x16x32_bf16(a0, b, acc[0][ft][g4], 0, 0, 0);
          acc[1][ft][g4] = __builtin_amdgcn_mfma_f32_16x16x32_bf16(a1, b, acc[1][ft][g4], 0, 0, 0);
        }
    }
#pragma unroll
    for (int mt = 0; mt < 2; ++mt)
#pragma unroll
      for (int ft = 0; ft < 2; ++ft) {
        int fi = 32 * w + 16 * ft + l15;
        float4 bb = bq[fi];
#pragma unroll
        for (int r = 0; r < 4; ++r) {
          int node = nb + mt * 16 + q * 4 + r;
          ushort4 o;
          o.x = f2bf(acc[mt][ft][0][r] + bb.x);
          o.y = f2bf(acc[mt][ft][1][r] + bb.y);
          o.z = f2bf(acc[mt][ft][2][r] + bb.z);
          o.w = f2bf(acc[mt][ft][3][r] + bb.w);
          xgq[(size_t)node * F + fi] = o;
        }
      }
  }
}

// ---------------- fused LSTM via MFMA, B register-persistent ----------------
// EXACT R5 body (measured 943 us, FETCH 1.03 GB, WRITE 149 MB, VGPR 128, no
// scratch). R6-R9 lesson, triple-confirmed: ANY structural perturbation of
// this loop (cross-step register state, t-conditional MFMA, double-buffered
// hs, custom barriers) tips it over the register cliff into scratch spill
// (+150..3000 MB traffic) or breaks the co-schedule. Do not touch the body.
#define LB 8
__global__ __launch_bounds__(256, 2) void k_lstm(const short* __restrict__ whb,
                                                 const ushort4* __restrict__ xgq,
                                                 const int* __restrict__ sel,
                                                 const int* __restrict__ lens,
                                                 float* __restrict__ hneigh) {
  __shared__ short hs[32 * HS_LD];   // 8704 B
  __shared__ int sel_l[32][9];
  const int tid = threadIdx.x;
  const int w = tid >> 6;
  const int l = tid & 63;
  const int l15 = l & 15, q = l >> 4;
  const int nb = blockIdx.x * LB;
  const char* xgb = (const char*)xgq;
  const int fi8 = (32 * w + l15) * 8;  // byte offset of this lane's ft=0 quad

  {
    int m = tid >> 3, t = tid & 7;
    int node = nb + (m >> 2), p = m & 3;
    sel_l[m][t] = sel[((size_t)p * N_NODES + node) * KARY + t];
  }
  {
    int* h32 = (int*)hs;
    for (int i = tid; i < 32 * HS_LD / 2; i += 256) h32[i] = 0;
  }
  uint32_t lp = 0;
#pragma unroll
  for (int i = 0; i < 8; ++i) lp |= (uint32_t)lens[nb + i] << (4 * i);

  // persistent B: breg[kt][g4][ft]  (128 VGPRs)
  bf16x8 breg[4][4][2];
#pragma unroll
  for (int kt = 0; kt < 4; ++kt)
#pragma unroll
    for (int g4 = 0; g4 < 4; ++g4)
#pragma unroll
      for (int ft = 0; ft < 2; ++ft)
        breg[kt][g4][ft] = *(const bf16x8*)(whb + (size_t)(g4 * 128 + 16 * ft + 32 * w + l15) * F + q * 8 + kt * 32);

  const short* abase = hs + l15 * HS_LD + q * 8;

  f32x4 cst[2][2];
#pragma unroll
  for (int mt = 0; mt < 2; ++mt)
#pragma unroll
    for (int ft = 0; ft < 2; ++ft) cst[mt][ft] = (f32x4){0.f, 0.f, 0.f, 0.f};

  __syncthreads();

  for (int t = 0; t < KARY; ++t) {
    // ---- prefetch this step's xg quads; latency hides under the MFMA phase
    uint2 xr[2][4][2];  // [mt][r][ft]: (i|f<<16, g|o<<16)
#pragma unroll
    for (int mt = 0; mt < 2; ++mt)
#pragma unroll
      for (int r = 0; r < 4; ++r) {
        int seq = mt * 16 + q * 4 + r;
        int v = sel_l[seq][t];
        v = v < 0 ? 0 : v;
        int off = (v << 10) + fi8;
        xr[mt][r][0] = *(const uint2*)(xgb + off);
        xr[mt][r][1] = *(const uint2*)(xgb + off + 128);
      }

    // ---- MFMA phase
    f32x4 acc[2][2][4];
#pragma unroll
    for (int mt = 0; mt < 2; ++mt)
#pragma unroll
      for (int ft = 0; ft < 2; ++ft)
#pragma unroll
        for (int g4 = 0; g4 < 4; ++g4) acc[mt][ft][g4] = (f32x4){0.f, 0.f, 0.f, 0.f};

#pragma unroll
    for (int kt = 0; kt < 4; ++kt) {
      bf16x8 a0 = *(const bf16x8*)(abase + 0 * 16 * HS_LD + kt * 32);
      bf16x8 a1 = *(const bf16x8*)(abase + 1 * 16 * HS_LD + kt * 32);
#pragma unroll
      for (int g4 = 0; g4 < 4; ++g4)
#pragma unroll
        for (int ft = 0; ft < 2; ++ft) {
          acc[0][ft][g4] = __builtin_amdgcn_mfma_f32_16x16x32_bf16(a0, breg[kt][g4][ft], acc[0][ft][g4], 0, 0, 0);
          acc[1][ft][g4] = __builtin_amdgcn_mfma_f32_16x16x32_bf16(a1, breg[kt][g4][ft], acc[1][ft][g4], 0, 0, 0);
        }
    }
    __syncthreads();  // all hs reads done before epilogue writes

    // ---- epilogue, vectorized over r (4 perms of one node; `live` uniform)
#pragma unroll
    for (int mt = 0; mt < 2; ++mt) {
      int len = (lp >> (4 * (mt * 4 + q))) & 15;
      bool live = t < len;
#pragma unroll
      for (int ft = 0; ft < 2; ++ft) {
        f32x4 xi, xf, xg_, xo;
#pragma unroll
        for (int r = 0; r < 4; ++r) {
          uint2 x = xr[mt][r][ft];
          xi[r] = ubf(x.x << 16);
          xf[r] = ubf(x.x & 0xffff0000u);
          xg_[r] = ubf(x.y << 16);
          xo[r] = ubf(x.y & 0xffff0000u);
        }
        f32x4 ii = sig4(acc[mt][ft][0] + xi);
        f32x4 ff = sig4(acc[mt][ft][1] + xf);
        f32x4 gg = tanh4(acc[mt][ft][2] + xg_);
        f32x4 oo = sig4(acc[mt][ft][3] + xo);
        f32x4 cn = ff * cst[mt][ft] + ii * gg;
        if (live) {
          cst[mt][ft] = cn;
          f32x4 hh = oo * tanh4(cn);
          int base = (mt * 16 + q * 4) * HS_LD + 32 * w + 16 * ft + l15;
#pragma unroll
          for (int r = 0; r < 4; ++r)
            hs[base + r * HS_LD] = (short)f2bf(hh[r]);
        }
      }
    }
    __syncthreads();
  }

#pragma unroll
  for (int mt = 0; mt < 2; ++mt) {
    int node = nb + mt * 4 + q;
#pragma unroll
    for (int ft = 0; ft < 2; ++ft) {
      int fi = 32 * w + 16 * ft + l15;
      f32x4 cc = cst[mt][ft];
      hneigh[(size_t)node * F + fi] = (cc.x + cc.y + cc.z + cc.w) * 0.25f;
    }
  }
}

// ---------------- head via MFMA: 64 nodes/block, N=64, K=256 ----------------
#define OS_LD 264  // 256 + 8 pad shorts
__global__ __launch_bounds__(256) void k_out(const float* __restrict__ feat,
                                             const float* __restrict__ hn,
                                             const short* __restrict__ wobT,
                                             const float* __restrict__ bias,
                                             float* __restrict__ out) {
  __shared__ short as_[64 * OS_LD];  // 33792 B
  const int tid = threadIdx.x;
  const int w = tid >> 6, l = tid & 63;
  const int l15 = l & 15, q = l >> 4;
  const int nb = blockIdx.x * 64;
#pragma unroll
  for (int i = 0; i < 16; ++i) {
    int idx = tid + i * 256;  // 4096 float4 = 64 rows x 256 cols
    int row = idx >> 6, c4 = (idx & 63) * 4;
    int node = nb + row;
    if (node > N_NODES - 1) node = N_NODES - 1;
    float4 v = (c4 < 128) ? *(const float4*)&feat[(size_t)node * F + c4]
                          : *(const float4*)&hn[(size_t)node * F + (c4 - 128)];
    ushort4 s;
    s.x = f2bf(v.x); s.y = f2bf(v.y); s.z = f2bf(v.z); s.w = f2bf(v.w);
    *(ushort4*)&as_[row * OS_LD + c4] = s;
  }
  __syncthreads();

  f32x4 acc[4];
#pragma unroll
  for (int nt = 0; nt < 4; ++nt) acc[nt] = (f32x4){0.f, 0.f, 0.f, 0.f};

  const short* ab = as_ + (w * 16 + l15) * OS_LD + q * 8;
#pragma unroll
  for (int kt = 0; kt < 8; ++kt) {
    bf16x8 a = *(const bf16x8*)(ab + kt * 32);
#pragma unroll
    for (int nt = 0; nt < 4; ++nt) {
      bf16x8 b = *(const bf16x8*)(wobT + (size_t)(nt * 16 + l15) * 256 + q * 8 + kt * 32);
      acc[nt] = __builtin_amdgcn_mfma_f32_16x16x32_bf16(a, b, acc[nt], 0, 0, 0);
    }
  }
#pragma unroll
  for (int nt = 0; nt < 4; ++nt) {
    int col = nt * 16 + l15;
    float bb = bias[col];
#pragma unroll
    for (int r = 0; r < 4; ++r) {
      int node = nb + w * 16 + q * 4 + r;
      if (node < N_NODES)
        out[(size_t)node * NOUT + col] = sigf(acc[nt][r] + bb);
    }
  }
}

extern "C" void kernel_launch(void* const* d_in, const int* in_sizes, int n_in,
                              void* d_out, int out_size, void* d_ws, size_t ws_size,
                              hipStream_t stream) {
  const float* feat = (const float*)d_in[0];
  const int2* adj = (const int2*)d_in[1];
  const float* w_ih = (const float*)d_in[2];
  const float* w_hh = (const float*)d_in[3];
  const float* b_ih = (const float*)d_in[4];
  const float* b_hh = (const float*)d_in[5];
  const float* weight = (const float*)d_in[6];
  const float* bias = (const float*)d_in[7];
  float* out = (float*)d_out;

  size_t off = 0;
  auto take = [&](size_t bytes) -> void* {
    void* p = (char*)d_ws + off;
    off += (bytes + 255) & ~(size_t)255;
    return p;
  };
  int* deg = (int*)take((size_t)N_NODES * 4);
  int* roff = (int*)take((size_t)N_NODES * 4);
  int* cursor = (int*)take((size_t)N_NODES * 4);
  int2* csr = (int2*)take((size_t)E_EDGES * 8);
  int* sel = (int*)take((size_t)NPERMS * N_NODES * KARY * 4);
  int* lens = (int*)take((size_t)N_NODES * 4);
  short* wihb = (short*)take((size_t)4 * F * F * 2);
  short* whb = (short*)take((size_t)4 * F * F * 2);
  short* wobT = (short*)take((size_t)NOUT * 2 * F * 2);
  float4* bq = (float4*)take((size_t)F * 16);
  ushort4* xgq = (ushort4*)take((size_t)N_NODES * F * 8);
  float* hn = (float*)take((size_t)N_NODES * F * 4);
  (void)ws_size; (void)in_sizes; (void)n_in; (void)out_size;

  hipMemsetAsync(deg, 0, (size_t)N_NODES * 4, stream);
  hipMemsetAsync(cursor, 0, (size_t)N_NODES * 4, stream);

  k_hist_prepw<<<HIST_BLK + 256, 256, 0, stream>>>(adj, deg, w_ih, w_hh, b_ih, b_hh,
                                                   weight, wihb, whb, wobT, bq);
  k_scan<<<1, 1024, 0, stream>>>(deg, roff);
  k_scatter<<<(E_EDGES + 255) / 256, 256, 0, stream>>>(adj, roff, cursor, csr);
  k_sel_xg<<<SEL_BLK + N_NODES / 32, 256, 0, stream>>>(csr, roff, deg, sel, lens,
                                                       feat, wihb, bq, xgq);
  k_lstm<<<N_NODES / LB, 256, 0, stream>>>(whb, xgq, sel, lens, hn);
  k_out<<<(N_NODES + 63) / 64, 256, 0, stream>>>(feat, hn, wobT, bias, out);
}

// Round 11
// 1294.565 us; speedup vs baseline: 1.2114x; 1.1176x over previous
//
#include <hip/hip_runtime.h>
#include <stdint.h>

#define N_NODES 100000
#define F 128
#define E_EDGES 1600000
#define KARY 8
#define NPERMS 4
#define NOUT 64

typedef __attribute__((ext_vector_type(8))) short bf16x8;
typedef __attribute__((ext_vector_type(4))) float f32x4;

// ---------------- threefry2x32 (JAX-exact, 20 rounds) ----------------
__device__ __forceinline__ uint32_t rotl32(uint32_t v, int r) {
  return (v << r) | (v >> (32 - r));
}
__device__ __forceinline__ void tf2x32(uint32_t k0, uint32_t k1, uint32_t& x0, uint32_t& x1) {
  uint32_t ks2 = k0 ^ k1 ^ 0x1BD11BDAu;
  x0 += k0; x1 += k1;
  x0 += x1; x1 = rotl32(x1,13); x1 ^= x0;
  x0 += x1; x1 = rotl32(x1,15); x1 ^= x0;
  x0 += x1; x1 = rotl32(x1,26); x1 ^= x0;
  x0 += x1; x1 = rotl32(x1, 6); x1 ^= x0;
  x0 += k1; x1 += ks2 + 1u;
  x0 += x1; x1 = rotl32(x1,17); x1 ^= x0;
  x0 += x1; x1 = rotl32(x1,29); x1 ^= x0;
  x0 += x1; x1 = rotl32(x1,16); x1 ^= x0;
  x0 += x1; x1 = rotl32(x1,24); x1 ^= x0;
  x0 += ks2; x1 += k0 + 2u;
  x0 += x1; x1 = rotl32(x1,13); x1 ^= x0;
  x0 += x1; x1 = rotl32(x1,15); x1 ^= x0;
  x0 += x1; x1 = rotl32(x1,26); x1 ^= x0;
  x0 += x1; x1 = rotl32(x1, 6); x1 ^= x0;
  x0 += k0; x1 += k1 + 3u;
  x0 += x1; x1 = rotl32(x1,17); x1 ^= x0;
  x0 += x1; x1 = rotl32(x1,29); x1 ^= x0;
  x0 += x1; x1 = rotl32(x1,16); x1 ^= x0;
  x0 += x1; x1 = rotl32(x1,24); x1 ^= x0;
  x0 += k1; x1 += ks2 + 4u;
  x0 += x1; x1 = rotl32(x1,13); x1 ^= x0;
  x0 += x1; x1 = rotl32(x1,15); x1 ^= x0;
  x0 += x1; x1 = rotl32(x1,26); x1 ^= x0;
  x0 += x1; x1 = rotl32(x1, 6); x1 ^= x0;
  x0 += ks2; x1 += k0 + 5u;
}

// bf16 helpers
__device__ __forceinline__ unsigned short f2bf(float f) {  // RNE
  uint32_t u = __float_as_uint(f);
  uint32_t r = (u + 0x7FFFu + ((u >> 16) & 1u)) >> 16;
  return (unsigned short)r;
}
__device__ __forceinline__ float ubf(uint32_t u) { return __uint_as_float(u); }

// native transcendentals: single v_exp_f32 / v_rcp_f32.
__device__ __forceinline__ f32x4 exp2v(f32x4 x) {
  f32x4 r;
  r.x = __builtin_amdgcn_exp2f(x.x);
  r.y = __builtin_amdgcn_exp2f(x.y);
  r.z = __builtin_amdgcn_exp2f(x.z);
  r.w = __builtin_amdgcn_exp2f(x.w);
  return r;
}
__device__ __forceinline__ f32x4 rcpv(f32x4 x) {
  f32x4 r;
  r.x = __builtin_amdgcn_rcpf(x.x);
  r.y = __builtin_amdgcn_rcpf(x.y);
  r.z = __builtin_amdgcn_rcpf(x.z);
  r.w = __builtin_amdgcn_rcpf(x.w);
  return r;
}
__device__ __forceinline__ f32x4 sig4(f32x4 x) {
  return rcpv(1.0f + exp2v(x * -1.44269504f));
}
__device__ __forceinline__ f32x4 tanh4(f32x4 x) {
  return 1.0f - 2.0f * rcpv(exp2v(x * 2.88539008f) + 1.0f);
}
__device__ __forceinline__ float sigf(float x) {
  return __builtin_amdgcn_rcpf(1.0f + __builtin_amdgcn_exp2f(x * -1.44269504f));
}

// ---------------- CSR build ----------------
#define HIST_BLK (E_EDGES / 256)  // 6250

// fat kernel: histogram (blocks 0..6249) + weight prep (next 256 blocks)
__global__ __launch_bounds__(256) void k_hist_prepw(
    const int2* __restrict__ adj, int* __restrict__ deg,
    const float* __restrict__ w_ih, const float* __restrict__ w_hh,
    const float* __restrict__ b_ih, const float* __restrict__ b_hh,
    const float* __restrict__ weight,
    short* __restrict__ wihb, short* __restrict__ whb,
    short* __restrict__ wobT, float4* __restrict__ bq) {
  int b = blockIdx.x;
  if (b < HIST_BLK) {
    int e = b * 256 + threadIdx.x;
    atomicAdd(&deg[adj[e].x], 1);
  } else {
    int t = (b - HIST_BLK) * 256 + threadIdx.x;  // 0 .. 65535
    wihb[t] = (short)f2bf(w_ih[t]);
    whb[t] = (short)f2bf(w_hh[t]);
    if (t < 2 * F * NOUT) {
      int n = t & 63, k = t >> 6;
      wobT[n * 256 + k] = (short)f2bf(weight[k * NOUT + n]);
    }
    if (t < F)
      bq[t] = make_float4(b_ih[t] + b_hh[t], b_ih[F + t] + b_hh[F + t],
                          b_ih[2 * F + t] + b_hh[2 * F + t], b_ih[3 * F + t] + b_hh[3 * F + t]);
  }
}

// ---------- coalesced 3-phase exclusive scan (replaces 1-block k_scan) ------
// Old k_scan: 1 block, ~300 uncoalesced passes over 400 KB through one CU's
// L1 port — est. 50-130 us of pure serialization on the critical path.
// Phase C is folded into the consumers: roff[n] = rpart[n] + boff[n>>10].
__global__ __launch_bounds__(1024) void k_scanA(const int* __restrict__ deg,
                                                int* __restrict__ rpart,
                                                int* __restrict__ bsum) {
  __shared__ int s[1024];
  int tid = threadIdx.x;
  int i = blockIdx.x * 1024 + tid;
  int v = (i < N_NODES) ? deg[i] : 0;
  s[tid] = v;
  __syncthreads();
  for (int off = 1; off < 1024; off <<= 1) {
    int t = (tid >= off) ? s[tid - off] : 0;
    __syncthreads();
    s[tid] += t;
    __syncthreads();
  }
  if (i < N_NODES) rpart[i] = s[tid] - v;  // block-local exclusive
  if (tid == 1023) bsum[blockIdx.x] = s[tid];
}

__global__ __launch_bounds__(128) void k_scanB(const int* __restrict__ bsum,
                                               int* __restrict__ boff) {
  __shared__ int s[128];
  int tid = threadIdx.x;
  int v = (tid < 98) ? bsum[tid] : 0;
  s[tid] = v;
  __syncthreads();
  for (int off = 1; off < 128; off <<= 1) {
    int t = (tid >= off) ? s[tid - off] : 0;
    __syncthreads();
    s[tid] += t;
    __syncthreads();
  }
  if (tid < 98) boff[tid] = s[tid] - v;  // exclusive over block sums
}

__global__ void k_scatter(const int2* __restrict__ adj, const int* __restrict__ rpart,
                          const int* __restrict__ boff, int* __restrict__ cursor,
                          int2* __restrict__ csr) {
  int e = blockIdx.x * blockDim.x + threadIdx.x;
  if (e < E_EDGES) {
    int2 a = adj[e];
    int pos = rpart[a.x] + boff[a.x >> 10] + atomicAdd(&cursor[a.x], 1);
    csr[pos] = make_int2(a.y, e);  // (dst, edge_id)
  }
}

#define HS_LD 136  // 128 + 8 pad shorts
#define SEL_BLK ((N_NODES + 255) / 256)  // 391

// fat kernel: top-8 selection (blocks 0..390, latency/VALU-bound) overlapped
// with x-side-gates MFMA GEMM (remaining 3125 blocks, memory/MFMA-bound).
__global__ __launch_bounds__(256) void k_sel_xg(
    const int2* __restrict__ csr, const int* __restrict__ rpart,
    const int* __restrict__ boff,
    const int* __restrict__ deg, int* __restrict__ sel, int* __restrict__ lens,
    const float* __restrict__ feat, const short* __restrict__ wihb,
    const float4* __restrict__ bq, ushort4* __restrict__ xgq) {
  __shared__ short as_[32 * HS_LD];
  if (blockIdx.x < SEL_BLK) {
    // ---------------- selection (4 perms fused, JAX lexsort-exact) ----------
    int n = blockIdx.x * 256 + threadIdx.x;
    if (n >= N_NODES) return;
    uint32_t pk0[NPERMS], pk1[NPERMS];
#pragma unroll
    for (int p = 0; p < NPERMS; ++p) {
      uint32_t a = 0u, b = (uint32_t)p;
      tf2x32(0u, 42u, a, b);
      pk0[p] = a; pk1[p] = b;
    }
    int off = rpart[n] + boff[n >> 10], d = deg[n];
    unsigned long long key[NPERMS][KARY];
    int nbr[NPERMS][KARY];
#pragma unroll
    for (int p = 0; p < NPERMS; ++p)
#pragma unroll
      for (int i = 0; i < KARY; ++i) { key[p][i] = ~0ULL; nbr[p][i] = -1; }
    for (int e = 0; e < d; ++e) {
      int2 ent = csr[off + e];
#pragma unroll
      for (int p = 0; p < NPERMS; ++p) {
        uint32_t x0 = 0u, x1 = (uint32_t)ent.y;
        tf2x32(pk0[p], pk1[p], x0, x1);
        uint32_t bits = x0 ^ x1;
        unsigned long long k = ((unsigned long long)(bits >> 9) << 21) | (unsigned)ent.y;
        if (k < key[p][KARY - 1]) {
          key[p][KARY - 1] = k; nbr[p][KARY - 1] = ent.x;
#pragma unroll
          for (int s = KARY - 1; s >= 1; --s) {
            if (key[p][s] < key[p][s - 1]) {
              unsigned long long tk = key[p][s]; key[p][s] = key[p][s - 1]; key[p][s - 1] = tk;
              int tn = nbr[p][s]; nbr[p][s] = nbr[p][s - 1]; nbr[p][s - 1] = tn;
            }
          }
        }
      }
    }
    int L = d < KARY ? d : KARY;
    lens[n] = L;
#pragma unroll
    for (int p = 0; p < NPERMS; ++p)
#pragma unroll
      for (int t = 0; t < KARY; ++t)
        sel[((size_t)p * N_NODES + n) * KARY + t] = (t < L) ? nbr[p][t] : -1;
  } else {
    // ---------------- x-side gates via MFMA: 32 nodes/block ----------------
    const int tid = threadIdx.x;
    const int w = tid >> 6, l = tid & 63;
    const int l15 = l & 15, q = l >> 4;
    const int nb = (blockIdx.x - SEL_BLK) * 32;
#pragma unroll
    for (int i = 0; i < 4; ++i) {
      int idx = tid + i * 256;  // 1024 float4 = 32 rows x 128 cols
      int row = idx >> 5, c4 = (idx & 31) * 4;
      float4 v = *(const float4*)&feat[(size_t)(nb + row) * F + c4];
      ushort4 s;
      s.x = f2bf(v.x); s.y = f2bf(v.y); s.z = f2bf(v.z); s.w = f2bf(v.w);
      *(ushort4*)&as_[row * HS_LD + c4] = s;
    }
    __syncthreads();

    f32x4 acc[2][2][4];
#pragma unroll
    for (int mt = 0; mt < 2; ++mt)
#pragma unroll
      for (int ft = 0; ft < 2; ++ft)
#pragma unroll
        for (int g4 = 0; g4 < 4; ++g4) acc[mt][ft][g4] = (f32x4){0.f, 0.f, 0.f, 0.f};

    const short* ab = as_ + l15 * HS_LD + q * 8;
#pragma unroll
    for (int kt = 0; kt < 4; ++kt) {
      bf16x8 a0 = *(const bf16x8*)(ab + kt * 32);
      bf16x8 a1 = *(const bf16x8*)(ab + 16 * HS_LD + kt * 32);
#pragma unroll
      for (int g4 = 0; g4 < 4; ++g4)
#pragma unroll
        for (int ft = 0; ft < 2; ++ft) {
          bf16x8 b = *(const bf16x8*)(wihb + (size_t)(g4 * 128 + 16 * ft + 32 * w + l15) * F + q * 8 + kt * 32);
          acc[0][ft][g4] = __builtin_amdgcn_mfma_f32_16x16x32_bf16(a0, b, acc[0][ft][g4], 0, 0, 0);
          acc[1][ft][g4] = __builtin_amdgcn_mfma_f32_16x16x32_bf16(a1, b, acc[1][ft][g4], 0, 0, 0);
        }
    }
#pragma unroll
    for (int mt = 0; mt < 2; ++mt)
#pragma unroll
      for (int ft = 0; ft < 2; ++ft) {
        int fi = 32 * w + 16 * ft + l15;
        float4 bb = bq[fi];
#pragma unroll
        for (int r = 0; r < 4; ++r) {
          int node = nb + mt * 16 + q * 4 + r;
          ushort4 o;
          o.x = f2bf(acc[mt][ft][0][r] + bb.x);
          o.y = f2bf(acc[mt][ft][1][r] + bb.y);
          o.z = f2bf(acc[mt][ft][2][r] + bb.z);
          o.w = f2bf(acc[mt][ft][3][r] + bb.w);
          xgq[(size_t)node * F + fi] = o;
        }
      }
  }
}

// ---------------- fused LSTM via MFMA + fused head ----------------
// t-loop = EXACT R5 body (943 us verified; R6-R9: any in-loop perturbation
// spills). POST-LOOP (breg dead, loop-live set unchanged): the k_out head is
// fused in — block stages [feat|hn] bf16 for its 8 nodes into the reused hs
// LDS region (16x264 rows; rows 8-15 stale-but-finite, their C rows are
// discarded) and computes sigmoid([feat,hn]@W+b) directly to `out`.
// Kills: k_out launch, 51 MB hn write, 51 MB hn read, 51 MB feat re-read.
#define LB 8
#define OS_LD 264
__global__ __launch_bounds__(256, 2) void k_lstm(const short* __restrict__ whb,
                                                 const ushort4* __restrict__ xgq,
                                                 const int* __restrict__ sel,
                                                 const int* __restrict__ lens,
                                                 const float* __restrict__ feat,
                                                 const short* __restrict__ wobT,
                                                 const float* __restrict__ bias,
                                                 float* __restrict__ out) {
  __shared__ short hs[32 * HS_LD];   // 8704 B; reused as 16x264 for the head
  __shared__ int sel_l[32][9];
  const int tid = threadIdx.x;
  const int w = tid >> 6;
  const int l = tid & 63;
  const int l15 = l & 15, q = l >> 4;
  const int nb = blockIdx.x * LB;
  const char* xgb = (const char*)xgq;
  const int fi8 = (32 * w + l15) * 8;  // byte offset of this lane's ft=0 quad

  {
    int m = tid >> 3, t = tid & 7;
    int node = nb + (m >> 2), p = m & 3;
    sel_l[m][t] = sel[((size_t)p * N_NODES + node) * KARY + t];
  }
  {
    int* h32 = (int*)hs;
    for (int i = tid; i < 32 * HS_LD / 2; i += 256) h32[i] = 0;
  }
  uint32_t lp = 0;
#pragma unroll
  for (int i = 0; i < 8; ++i) lp |= (uint32_t)lens[nb + i] << (4 * i);

  // persistent B: breg[kt][g4][ft]  (128 VGPRs)
  bf16x8 breg[4][4][2];
#pragma unroll
  for (int kt = 0; kt < 4; ++kt)
#pragma unroll
    for (int g4 = 0; g4 < 4; ++g4)
#pragma unroll
      for (int ft = 0; ft < 2; ++ft)
        breg[kt][g4][ft] = *(const bf16x8*)(whb + (size_t)(g4 * 128 + 16 * ft + 32 * w + l15) * F + q * 8 + kt * 32);

  const short* abase = hs + l15 * HS_LD + q * 8;

  f32x4 cst[2][2];
#pragma unroll
  for (int mt = 0; mt < 2; ++mt)
#pragma unroll
    for (int ft = 0; ft < 2; ++ft) cst[mt][ft] = (f32x4){0.f, 0.f, 0.f, 0.f};

  __syncthreads();

  for (int t = 0; t < KARY; ++t) {
    // ---- prefetch this step's xg quads; latency hides under the MFMA phase
    uint2 xr[2][4][2];  // [mt][r][ft]: (i|f<<16, g|o<<16)
#pragma unroll
    for (int mt = 0; mt < 2; ++mt)
#pragma unroll
      for (int r = 0; r < 4; ++r) {
        int seq = mt * 16 + q * 4 + r;
        int v = sel_l[seq][t];
        v = v < 0 ? 0 : v;
        int off = (v << 10) + fi8;
        xr[mt][r][0] = *(const uint2*)(xgb + off);
        xr[mt][r][1] = *(const uint2*)(xgb + off + 128);
      }

    // ---- MFMA phase
    f32x4 acc[2][2][4];
#pragma unroll
    for (int mt = 0; mt < 2; ++mt)
#pragma unroll
      for (int ft = 0; ft < 2; ++ft)
#pragma unroll
        for (int g4 = 0; g4 < 4; ++g4) acc[mt][ft][g4] = (f32x4){0.f, 0.f, 0.f, 0.f};

#pragma unroll
    for (int kt = 0; kt < 4; ++kt) {
      bf16x8 a0 = *(const bf16x8*)(abase + 0 * 16 * HS_LD + kt * 32);
      bf16x8 a1 = *(const bf16x8*)(abase + 1 * 16 * HS_LD + kt * 32);
#pragma unroll
      for (int g4 = 0; g4 < 4; ++g4)
#pragma unroll
        for (int ft = 0; ft < 2; ++ft) {
          acc[0][ft][g4] = __builtin_amdgcn_mfma_f32_16x16x32_bf16(a0, breg[kt][g4][ft], acc[0][ft][g4], 0, 0, 0);
          acc[1][ft][g4] = __builtin_amdgcn_mfma_f32_16x16x32_bf16(a1, breg[kt][g4][ft], acc[1][ft][g4], 0, 0, 0);
        }
    }
    __syncthreads();  // all hs reads done before epilogue writes

    // ---- epilogue, vectorized over r (4 perms of one node; `live` uniform)
#pragma unroll
    for (int mt = 0; mt < 2; ++mt) {
      int len = (lp >> (4 * (mt * 4 + q))) & 15;
      bool live = t < len;
#pragma unroll
      for (int ft = 0; ft < 2; ++ft) {
        f32x4 xi, xf, xg_, xo;
#pragma unroll
        for (int r = 0; r < 4; ++r) {
          uint2 x = xr[mt][r][ft];
          xi[r] = ubf(x.x << 16);
          xf[r] = ubf(x.x & 0xffff0000u);
          xg_[r] = ubf(x.y << 16);
          xo[r] = ubf(x.y & 0xffff0000u);
        }
        f32x4 ii = sig4(acc[mt][ft][0] + xi);
        f32x4 ff = sig4(acc[mt][ft][1] + xf);
        f32x4 gg = tanh4(acc[mt][ft][2] + xg_);
        f32x4 oo = sig4(acc[mt][ft][3] + xo);
        f32x4 cn = ff * cst[mt][ft] + ii * gg;
        if (live) {
          cst[mt][ft] = cn;
          f32x4 hh = oo * tanh4(cn);
          int base = (mt * 16 + q * 4) * HS_LD + 32 * w + 16 * ft + l15;
#pragma unroll
          for (int r = 0; r < 4; ++r)
            hs[base + r * HS_LD] = (short)f2bf(hh[r]);
        }
      }
    }
    __syncthreads();
  }

  // ================= fused head: out[8][64] = sig([feat|hn]@W + b) =========
  short* as2 = hs;  // reinterpret as [16][OS_LD]; need 16*264*2=8448 <= 8704 B

  // stage hn (from cst) into cols 128..255 of rows 0..7
#pragma unroll
  for (int mt = 0; mt < 2; ++mt)
#pragma unroll
    for (int ft = 0; ft < 2; ++ft) {
      f32x4 cc = cst[mt][ft];
      float hv = (cc.x + cc.y + cc.z + cc.w) * 0.25f;
      as2[(mt * 4 + q) * OS_LD + 128 + 32 * w + 16 * ft + l15] = (short)f2bf(hv);
    }
  // stage feat bf16 into cols 0..127 of rows 0..7 (8x128 = 256 float4)
  {
    int row = tid >> 5, c4 = (tid & 31) * 4;
    float4 v = *(const float4*)&feat[(size_t)(nb + row) * F + c4];
    ushort4 s;
    s.x = f2bf(v.x); s.y = f2bf(v.y); s.z = f2bf(v.z); s.w = f2bf(v.w);
    *(ushort4*)&as2[row * OS_LD + c4] = s;
  }
  float bb = bias[16 * w + l15];
  __syncthreads();

  // wave w computes out cols [16w,16w+16): 8 MFMA over K=256
  f32x4 oacc = (f32x4){0.f, 0.f, 0.f, 0.f};
  const short* ab2 = as2 + l15 * OS_LD + q * 8;
#pragma unroll
  for (int kt = 0; kt < 8; ++kt) {
    bf16x8 a = *(const bf16x8*)(ab2 + kt * 32);  // rows 8-15 garbage, discarded
    bf16x8 b = *(const bf16x8*)(wobT + (size_t)(16 * w + l15) * 256 + q * 8 + kt * 32);
    oacc = __builtin_amdgcn_mfma_f32_16x16x32_bf16(a, b, oacc, 0, 0, 0);
  }
  if (q < 2) {  // C rows q*4+r in 0..7 are the valid nodes
#pragma unroll
    for (int r = 0; r < 4; ++r) {
      int node = nb + q * 4 + r;
      out[(size_t)node * NOUT + 16 * w + l15] = sigf(oacc[r] + bb);
    }
  }
}

extern "C" void kernel_launch(void* const* d_in, const int* in_sizes, int n_in,
                              void* d_out, int out_size, void* d_ws, size_t ws_size,
                              hipStream_t stream) {
  const float* feat = (const float*)d_in[0];
  const int2* adj = (const int2*)d_in[1];
  const float* w_ih = (const float*)d_in[2];
  const float* w_hh = (const float*)d_in[3];
  const float* b_ih = (const float*)d_in[4];
  const float* b_hh = (const float*)d_in[5];
  const float* weight = (const float*)d_in[6];
  const float* bias = (const float*)d_in[7];
  float* out = (float*)d_out;

  size_t off = 0;
  auto take = [&](size_t bytes) -> void* {
    void* p = (char*)d_ws + off;
    off += (bytes + 255) & ~(size_t)255;
    return p;
  };
  int* deg = (int*)take((size_t)N_NODES * 4);
  int* rpart = (int*)take((size_t)N_NODES * 4);
  int* cursor = (int*)take((size_t)N_NODES * 4);
  int2* csr = (int2*)take((size_t)E_EDGES * 8);
  int* sel = (int*)take((size_t)NPERMS * N_NODES * KARY * 4);
  int* lens = (int*)take((size_t)N_NODES * 4);
  short* wihb = (short*)take((size_t)4 * F * F * 2);
  short* whb = (short*)take((size_t)4 * F * F * 2);
  short* wobT = (short*)take((size_t)NOUT * 2 * F * 2);
  float4* bq = (float4*)take((size_t)F * 16);
  ushort4* xgq = (ushort4*)take((size_t)N_NODES * F * 8);
  int* bsum = (int*)take(128 * 4);
  int* boff = (int*)take(128 * 4);
  (void)ws_size; (void)in_sizes; (void)n_in; (void)out_size;

  hipMemsetAsync(deg, 0, (size_t)N_NODES * 4, stream);
  hipMemsetAsync(cursor, 0, (size_t)N_NODES * 4, stream);

  k_hist_prepw<<<HIST_BLK + 256, 256, 0, stream>>>(adj, deg, w_ih, w_hh, b_ih, b_hh,
                                                   weight, wihb, whb, wobT, bq);
  k_scanA<<<98, 1024, 0, stream>>>(deg, rpart, bsum);
  k_scanB<<<1, 128, 0, stream>>>(bsum, boff);
  k_scatter<<<(E_EDGES + 255) / 256, 256, 0, stream>>>(adj, rpart, boff, cursor, csr);
  k_sel_xg<<<SEL_BLK + N_NODES / 32, 256, 0, stream>>>(csr, rpart, boff, deg, sel, lens,
                                                       feat, wihb, bq, xgq);
  k_lstm<<<N_NODES / LB, 256, 0, stream>>>(whb, xgq, sel, lens, feat, wobT, bias, out);
}